// Round 6
// baseline (345.706 us; speedup 1.0000x reference)
//
#include <hip/hip_runtime.h>
#include <cmath>

typedef __bf16 bf16x8 __attribute__((ext_vector_type(8)));
typedef float  f32x4  __attribute__((ext_vector_type(4)));

#define B_  8
#define L_  1024
#define DM  256
#define DI  512
#define DS  16
#define DTR 16
#define M_  (B_*L_)
#define NC  32     // scan chunks
#define CT  32     // steps per chunk

__device__ inline float softplus_f(float z){
  return (z > 20.f) ? z : __logf(1.f + __expf(z));
}
__device__ inline float silu_f(float z){
  return z / (1.f + __expf(-z));
}

// ---------------- dtype probe: are inputs fp32 or bf16? ----------------
__global__ __launch_bounds__(256) void probe_k(const void* x, int* flag){
  __shared__ int sbad[256];
  int tid = threadIdx.x;
  const unsigned short* u = (const unsigned short*)x;
  int bad = 0;
  for (int i = tid; i < 4096; i += 256){
    unsigned short v = u[2*i];
    int e = (v >> 7) & 0xFF;
    if (e >= 160 || e < 96) bad++;
  }
  sbad[tid] = bad;
  __syncthreads();
  if (tid == 0){
    int t = 0;
    for (int i=0;i<256;i++) t += sbad[i];
    *flag = (t > 1024) ? 1 : 0;   // 1 = inputs are fp32
  }
}

// ---------------- convert all inputs to canonical bf16 ----------------
struct CvtJob { const void* src; __bf16* dst; int n; };
struct CvtArgs { CvtJob j[23]; };

__global__ __launch_bounds__(256) void cvt_k(CvtArgs a, const int* flag){
  int e = blockIdx.x*256 + threadIdx.x;
  const int f = *flag;
  #pragma unroll 1
  for (int jj=0; jj<23; jj++){
    int n = a.j[jj].n;
    if (e < n){
      if (f) a.j[jj].dst[e] = (__bf16)(((const float*)a.j[jj].src)[e]);
      else   a.j[jj].dst[e] = ((const __bf16*)a.j[jj].src)[e];
      return;
    }
    e -= n;
  }
}

// exact-f32 copy of ALog (both dirs)
__global__ __launch_bounds__(256) void cvtA_k(const void* a0, const void* a1,
                                              float* o0, float* o1, const int* flag){
  int gid = blockIdx.x*256 + threadIdx.x;   // 16384
  const int f = *flag;
  const void* src = (gid < 8192) ? a0 : a1;
  float* dst = (gid < 8192) ? o0 : o1;
  int i = gid & 8191;
  dst[i] = f ? ((const float*)src)[i] : (float)((const __bf16*)src)[i];
}

// ---------------- prep: transpose all weight matrices (bf16 in) ----------------
struct PrepJob { const __bf16* src; void* dst; int rows; int cols; int f32out; };
struct PrepArgs { PrepJob j[11]; };

__global__ __launch_bounds__(256) void prep_k(PrepArgs a){
  int e = blockIdx.x*256 + threadIdx.x;
  #pragma unroll 1
  for (int jj=0; jj<11; jj++){
    int sz = a.j[jj].rows * a.j[jj].cols;
    if (e < sz){
      int cols = a.j[jj].cols;
      int r = e / cols, c = e - r*cols;
      float v = (float)a.j[jj].src[e];
      if (a.j[jj].f32out) ((float*)a.j[jj].dst)[c*a.j[jj].rows + r] = v;
      else ((__bf16*)a.j[jj].dst)[(long)c*a.j[jj].rows + r] = (__bf16)v;
      return;
    }
    e -= sz;
  }
}

// ---------------- LayerNorm ----------------
__global__ __launch_bounds__(256) void ln_k(const __bf16* x, const __bf16* g,
                                            const __bf16* bb, __bf16* xn){
  const int row = blockIdx.x;
  const int d = threadIdx.x;
  float v = (float)x[(long)row*DM + d];
  float s = v, q = v*v;
  #pragma unroll
  for (int off=32; off>0; off>>=1){
    s += __shfl_down(s, off);
    q += __shfl_down(q, off);
  }
  __shared__ float ss[4], sq[4];
  int w = d >> 6, ln = d & 63;
  if (ln == 0){ ss[w] = s; sq[w] = q; }
  __syncthreads();
  s = ss[0]+ss[1]+ss[2]+ss[3];
  q = sq[0]+sq[1]+sq[2]+sq[3];
  float mu  = s * (1.f/DM);
  float var = q * (1.f/DM) - mu*mu;
  float xnv = (v - mu) * rsqrtf(var + 1e-5f) * (float)g[d] + (float)bb[d];
  xn[(long)row*DM + d] = (__bf16)xnv;
}

// ---------------- generic MFMA GEMM: C[M][N] = A[M][K] * Bt[N][K]^T ----------------
// EPI 0: split store (c<DI -> C [xz], c>=DI -> res, both ldc=DI); A rows flipped when dir==1
// EPI 1: f32 store
// EPI 2: bf16 store into concat buffer colOff=dir*DM; C rows flipped when dir==1
// EPI 3: store + bias + residual; dtype per *outflag
template<int WMT,int WNT,int BWM,int BWN,int EPI>
__global__ __launch_bounds__(64*BWM*BWN) void gemm_k(
    const __bf16* A0, const __bf16* A1,
    const __bf16* B0, const __bf16* B1,
    void* C0, void* C1,
    int K, int lda, int ldb, int ldc,
    const __bf16* bias, const __bf16* resid, const int* outflag)
{
  const int dir = blockIdx.z;
  const __bf16* A  = dir ? A1 : A0;
  const __bf16* Bt = dir ? B1 : B0;
  char* C = (char*)(dir ? C1 : C0);
  // EPI==0: res buffers smuggled through bias/resid
  __bf16* resW = (EPI==0) ? (__bf16*)(dir ? resid : bias) : nullptr;
  const int tid  = threadIdx.x;
  const int lane = tid & 63;
  const int wid  = tid >> 6;
  const int wm = wid % BWM;
  const int wn = wid / BWM;
  const int mBase = (blockIdx.x*BWM + wm) * (WMT*16);
  const int nBase = (blockIdx.y*BWN + wn) * (WNT*16);
  const int lm = lane & 15;
  const int kq = (lane >> 4) * 8;
  const int of = (EPI==3 && outflag) ? *outflag : 0;

  long aoff[WMT];
  #pragma unroll
  for (int i=0;i<WMT;i++){
    int r = mBase + i*16 + lm;
    if (EPI==0 && dir==1){ int b = r >> 10, t = r & (L_-1); r = (b<<10) + (L_-1-t); }
    aoff[i] = (long)r * lda + kq;
  }
  long boff[WNT];
  #pragma unroll
  for (int j=0;j<WNT;j++) boff[j] = (long)(nBase + j*16 + lm) * ldb + kq;

  f32x4 acc[WMT][WNT] = {};
  for (int k0=0; k0<K; k0+=32){
    bf16x8 af[WMT], bfr[WNT];
    #pragma unroll
    for (int i=0;i<WMT;i++) af[i]  = *(const bf16x8*)(A  + aoff[i] + k0);
    #pragma unroll
    for (int j=0;j<WNT;j++) bfr[j] = *(const bf16x8*)(Bt + boff[j] + k0);
    #pragma unroll
    for (int i=0;i<WMT;i++)
      #pragma unroll
      for (int j=0;j<WNT;j++)
        acc[i][j] = __builtin_amdgcn_mfma_f32_16x16x32_bf16(af[i], bfr[j], acc[i][j], 0,0,0);
  }

  const int coff = (EPI==2) ? dir*DM : 0;
  #pragma unroll
  for (int i=0;i<WMT;i++){
    #pragma unroll
    for (int rr=0;rr<4;rr++){
      int r = mBase + i*16 + (lane>>4)*4 + rr;
      int rOut = r;
      if (EPI==2 && dir==1){ int b = r >> 10, t = r & (L_-1); rOut = (b<<10) + (L_-1-t); }
      #pragma unroll
      for (int j=0;j<WNT;j++){
        int c = nBase + j*16 + lm;
        float v = acc[i][j][rr];
        if (EPI==0){
          if (c < DI) ((__bf16*)C)[(long)r*DI + c] = (__bf16)v;
          else        resW[(long)r*DI + (c-DI)]    = (__bf16)v;
        } else if (EPI==3){
          v += (float)bias[c] + (float)resid[(long)r*DM + c];
          if (of) ((float*)C)[(long)r*ldc + c] = v;
          else    ((__bf16*)C)[(long)r*ldc + c] = (__bf16)v;
        } else if (EPI==1){
          ((float*)C)[(long)r*ldc + c] = v;
        } else {
          ((__bf16*)C)[(long)rOut*ldc + coff + c] = (__bf16)v;
        }
      }
    }
  }
}

// ---------------- causal depthwise conv (DC=4) + SiLU ----------------
// reads compact xz [M][DI], writes xsc [M][DI]
__global__ __launch_bounds__(256) void conv_k(
    const __bf16* xz0, const __bf16* xz1,
    const float* cw0, const float* cw1,
    const __bf16* cb0, const __bf16* cb1,
    __bf16* xs0, __bf16* xs1)
{
  const int dir = blockIdx.z;
  const __bf16* xz = dir ? xz1 : xz0;
  const float*  cw = dir ? cw1 : cw0;
  const __bf16* cb = dir ? cb1 : cb0;
  __bf16* xs = dir ? xs1 : xs0;

  int gid = blockIdx.x*256 + threadIdx.x;
  int c8 = gid & 63;
  int t  = (gid >> 6) & (L_-1);
  int b  = gid >> 16;
  int cbase = c8*8;

  float acc[8];
  bf16x8 bb = *(const bf16x8*)(cb + cbase);
  #pragma unroll
  for (int c=0;c<8;c++) acc[c] = (float)bb[c];
  #pragma unroll
  for (int j=0;j<4;j++){
    int tj = t - 3 + j;
    if (tj >= 0){
      bf16x8 xv = *(const bf16x8*)(xz + ((long)(b*L_ + tj))*DI + cbase);
      #pragma unroll
      for (int c=0;c<8;c++) acc[c] += (float)xv[c] * cw[j*DI + cbase + c];
    }
  }
  bf16x8 outv;
  #pragma unroll
  for (int c=0;c<8;c++) outv[c] = (__bf16)silu_f(acc[c]);
  *(bf16x8*)(xs + ((long)(b*L_ + t))*DI + cbase) = outv;
}

// ============ chunked scan phase A: local scan + chunk summaries ============
// LDS-free: dlt/B read as wave-uniform f32x4 global loads (L1-resident).
__global__ __launch_bounds__(256) void scanA_k(
    const float* xd0, const float* xd1,
    const __bf16* xs0, const __bf16* xs1,
    const float* dw0, const float* dw1,
    const __bf16* dtB0, const __bf16* dtB1,
    const float* ALf0, const float* ALf1,
    float* hend, float* sumd)
{
  const int dir = blockIdx.z;
  const float*  xd  = dir ? xd1 : xd0;
  const __bf16* xs  = dir ? xs1 : xs0;
  const float*  dw  = dir ? dw1 : dw0;
  const __bf16* dtB = dir ? dtB1 : dtB0;
  const float*  ALf = dir ? ALf1 : ALf0;

  const int b   = blockIdx.y;
  const int c   = blockIdx.x >> 1;
  const int dg_ = blockIdx.x & 1;
  const int tid = threadIdx.x;
  const int d   = dg_*256 + tid;
  const int db  = dir*8 + b;
  const long row0 = (long)b*L_ + c*CT;
  const float* rp0 = xd + row0*48;

  float dwq[16];
  { const f32x4* p = (const f32x4*)(dw + d*DTR);
    #pragma unroll
    for (int q=0;q<4;q++){ f32x4 v=p[q]; dwq[q*4]=v[0]; dwq[q*4+1]=v[1]; dwq[q*4+2]=v[2]; dwq[q*4+3]=v[3]; } }
  float A[16];
  { const f32x4* p = (const f32x4*)(ALf + d*DS);
    #pragma unroll
    for (int q=0;q<4;q++){ f32x4 v=p[q];
      A[q*4]=-__expf(v[0]); A[q*4+1]=-__expf(v[1]); A[q*4+2]=-__expf(v[2]); A[q*4+3]=-__expf(v[3]); } }
  bool pow_ok = true;
  #pragma unroll
  for (int n=0;n<16;n++) pow_ok = pow_ok && (fabsf(A[n] + (float)(n+1)) < 0.003f*(n+1));
  const float dtbv = (float)dtB[d];

  float h[16];
  #pragma unroll
  for (int n=0;n<16;n++) h[n]=0.f;
  float sdelta = 0.f;

  if (pow_ok){
    #pragma unroll 2
    for (int t=0;t<CT;t++){
      const float* rp = rp0 + t*48;
      f32x4 q0 = *(const f32x4*)(rp);
      f32x4 q1 = *(const f32x4*)(rp+4);
      f32x4 q2 = *(const f32x4*)(rp+8);
      f32x4 q3 = *(const f32x4*)(rp+12);
      f32x4 b0 = *(const f32x4*)(rp+16);
      f32x4 b1 = *(const f32x4*)(rp+20);
      f32x4 b2 = *(const f32x4*)(rp+24);
      f32x4 b3 = *(const f32x4*)(rp+28);
      float z = dtbv;
      z += q0[0]*dwq[0]+q0[1]*dwq[1]+q0[2]*dwq[2]+q0[3]*dwq[3];
      z += q1[0]*dwq[4]+q1[1]*dwq[5]+q1[2]*dwq[6]+q1[3]*dwq[7];
      z += q2[0]*dwq[8]+q2[1]*dwq[9]+q2[2]*dwq[10]+q2[3]*dwq[11];
      z += q3[0]*dwq[12]+q3[1]*dwq[13]+q3[2]*dwq[14]+q3[3]*dwq[15];
      float delta = softplus_f(z);
      sdelta += delta;
      float xv = (float)xs[(row0+t)*DI + d];
      float dx = delta*xv;
      float e1 = __expf(-delta);
      float dA = e1;
      float Bv[16] = {b0[0],b0[1],b0[2],b0[3], b1[0],b1[1],b1[2],b1[3],
                      b2[0],b2[1],b2[2],b2[3], b3[0],b3[1],b3[2],b3[3]};
      #pragma unroll
      for (int n=0;n<16;n++){
        h[n] = dA*h[n] + dx*Bv[n];
        dA *= e1;
      }
    }
  } else {
    #pragma unroll 2
    for (int t=0;t<CT;t++){
      const float* rp = rp0 + t*48;
      f32x4 q0 = *(const f32x4*)(rp);
      f32x4 q1 = *(const f32x4*)(rp+4);
      f32x4 q2 = *(const f32x4*)(rp+8);
      f32x4 q3 = *(const f32x4*)(rp+12);
      f32x4 b0 = *(const f32x4*)(rp+16);
      f32x4 b1 = *(const f32x4*)(rp+20);
      f32x4 b2 = *(const f32x4*)(rp+24);
      f32x4 b3 = *(const f32x4*)(rp+28);
      float z = dtbv;
      z += q0[0]*dwq[0]+q0[1]*dwq[1]+q0[2]*dwq[2]+q0[3]*dwq[3];
      z += q1[0]*dwq[4]+q1[1]*dwq[5]+q1[2]*dwq[6]+q1[3]*dwq[7];
      z += q2[0]*dwq[8]+q2[1]*dwq[9]+q2[2]*dwq[10]+q2[3]*dwq[11];
      z += q3[0]*dwq[12]+q3[1]*dwq[13]+q3[2]*dwq[14]+q3[3]*dwq[15];
      float delta = softplus_f(z);
      sdelta += delta;
      float xv = (float)xs[(row0+t)*DI + d];
      float dx = delta*xv;
      float Bv[16] = {b0[0],b0[1],b0[2],b0[3], b1[0],b1[1],b1[2],b1[3],
                      b2[0],b2[1],b2[2],b2[3], b3[0],b3[1],b3[2],b3[3]};
      #pragma unroll
      for (int n=0;n<16;n++)
        h[n] = __expf(delta*A[n])*h[n] + dx*Bv[n];
    }
  }

  long hb = (((long)db*NC + c)*DI + d)*16;
  f32x4* hp = (f32x4*)(hend + hb);
  #pragma unroll
  for (int q=0;q<4;q++){ f32x4 v; v[0]=h[q*4]; v[1]=h[q*4+1]; v[2]=h[q*4+2]; v[3]=h[q*4+3]; hp[q]=v; }
  sumd[((long)db*NC + c)*DI + d] = sdelta;
}

// ============ phase B: chain chunk summaries sequentially ============
__global__ __launch_bounds__(256) void scanB_k(
    const float* ALf0, const float* ALf1,
    const float* hend, const float* sumd, float* Hbuf)
{
  int gid = blockIdx.x*256 + threadIdx.x;   // 131072
  int n  = gid & 15;
  int d  = (gid>>4) & 511;
  int db = gid >> 13;
  const float* ALf = (db>=8) ? ALf1 : ALf0;
  float A_dn = -__expf(ALf[d*DS + n]);
  float H = 0.f;
  #pragma unroll 1
  for (int c=0;c<NC;c++){
    long base = (((long)db*NC + c)*DI + d)*16 + n;
    Hbuf[base] = H;
    float S = sumd[((long)db*NC + c)*DI + d];
    H = hend[base] + __expf(A_dn*S)*H;
  }
}

// ============ phase C: re-scan seeded from Hbuf; y + gate; in-place into res ============
__global__ __launch_bounds__(256) void scanC_k(
    const float* xd0, const float* xd1,
    const __bf16* xs0, const __bf16* xs1,
    __bf16* res0, __bf16* res1,            // [M][DI]; read gate, overwrite with yg
    const float* dw0, const float* dw1,
    const __bf16* dtB0, const __bf16* dtB1,
    const float* ALf0, const float* ALf1,
    const __bf16* Dp0, const __bf16* Dp1,
    const float* Hbuf)
{
  const int dir = blockIdx.z;
  const float*  xd  = dir ? xd1 : xd0;
  const __bf16* xs  = dir ? xs1 : xs0;
  __bf16*       res = dir ? res1 : res0;
  const float*  dw  = dir ? dw1 : dw0;
  const __bf16* dtB = dir ? dtB1 : dtB0;
  const float*  ALf = dir ? ALf1 : ALf0;
  const __bf16* Dp  = dir ? Dp1 : Dp0;

  const int b   = blockIdx.y;
  const int c   = blockIdx.x >> 1;
  const int dg_ = blockIdx.x & 1;
  const int tid = threadIdx.x;
  const int d   = dg_*256 + tid;
  const int db  = dir*8 + b;
  const long row0 = (long)b*L_ + c*CT;
  const float* rp0 = xd + row0*48;

  float dwq[16];
  { const f32x4* p = (const f32x4*)(dw + d*DTR);
    #pragma unroll
    for (int q=0;q<4;q++){ f32x4 v=p[q]; dwq[q*4]=v[0]; dwq[q*4+1]=v[1]; dwq[q*4+2]=v[2]; dwq[q*4+3]=v[3]; } }
  float A[16];
  { const f32x4* p = (const f32x4*)(ALf + d*DS);
    #pragma unroll
    for (int q=0;q<4;q++){ f32x4 v=p[q];
      A[q*4]=-__expf(v[0]); A[q*4+1]=-__expf(v[1]); A[q*4+2]=-__expf(v[2]); A[q*4+3]=-__expf(v[3]); } }
  bool pow_ok = true;
  #pragma unroll
  for (int n=0;n<16;n++) pow_ok = pow_ok && (fabsf(A[n] + (float)(n+1)) < 0.003f*(n+1));
  const float dtbv = (float)dtB[d];

  float h[16];
  { long hb = (((long)db*NC + c)*DI + d)*16;
    const f32x4* p = (const f32x4*)(Hbuf + hb);
    #pragma unroll
    for (int q=0;q<4;q++){ f32x4 v = p[q]; h[q*4]=v[0]; h[q*4+1]=v[1]; h[q*4+2]=v[2]; h[q*4+3]=v[3]; } }
  const float Dpv = (float)Dp[d];

  if (pow_ok){
    #pragma unroll 2
    for (int t=0;t<CT;t++){
      long row = row0 + t;
      const float* rp = rp0 + t*48;
      f32x4 q0 = *(const f32x4*)(rp);
      f32x4 q1 = *(const f32x4*)(rp+4);
      f32x4 q2 = *(const f32x4*)(rp+8);
      f32x4 q3 = *(const f32x4*)(rp+12);
      f32x4 b0 = *(const f32x4*)(rp+16);
      f32x4 b1 = *(const f32x4*)(rp+20);
      f32x4 b2 = *(const f32x4*)(rp+24);
      f32x4 b3 = *(const f32x4*)(rp+28);
      f32x4 c0 = *(const f32x4*)(rp+32);
      f32x4 c1 = *(const f32x4*)(rp+36);
      f32x4 c2 = *(const f32x4*)(rp+40);
      f32x4 c3 = *(const f32x4*)(rp+44);
      float z = dtbv;
      z += q0[0]*dwq[0]+q0[1]*dwq[1]+q0[2]*dwq[2]+q0[3]*dwq[3];
      z += q1[0]*dwq[4]+q1[1]*dwq[5]+q1[2]*dwq[6]+q1[3]*dwq[7];
      z += q2[0]*dwq[8]+q2[1]*dwq[9]+q2[2]*dwq[10]+q2[3]*dwq[11];
      z += q3[0]*dwq[12]+q3[1]*dwq[13]+q3[2]*dwq[14]+q3[3]*dwq[15];
      float delta = softplus_f(z);
      float xv = (float)xs[row*DI + d];
      float dx = delta*xv;
      float e1 = __expf(-delta);
      float dA = e1;
      float Bv[16] = {b0[0],b0[1],b0[2],b0[3], b1[0],b1[1],b1[2],b1[3],
                      b2[0],b2[1],b2[2],b2[3], b3[0],b3[1],b3[2],b3[3]};
      float Cv[16] = {c0[0],c0[1],c0[2],c0[3], c1[0],c1[1],c1[2],c1[3],
                      c2[0],c2[1],c2[2],c2[3], c3[0],c3[1],c3[2],c3[3]};
      float p = 0.f;
      #pragma unroll
      for (int n=0;n<16;n++){
        h[n] = dA*h[n] + dx*Bv[n];
        p += h[n]*Cv[n];
        dA *= e1;
      }
      float yv = p + Dpv*xv;
      float rv = (float)res[row*DI + d];
      res[row*DI + d] = (__bf16)(yv * silu_f(rv));
    }
  } else {
    #pragma unroll 2
    for (int t=0;t<CT;t++){
      long row = row0 + t;
      const float* rp = rp0 + t*48;
      f32x4 q0 = *(const f32x4*)(rp);
      f32x4 q1 = *(const f32x4*)(rp+4);
      f32x4 q2 = *(const f32x4*)(rp+8);
      f32x4 q3 = *(const f32x4*)(rp+12);
      f32x4 b0 = *(const f32x4*)(rp+16);
      f32x4 b1 = *(const f32x4*)(rp+20);
      f32x4 b2 = *(const f32x4*)(rp+24);
      f32x4 b3 = *(const f32x4*)(rp+28);
      f32x4 c0 = *(const f32x4*)(rp+32);
      f32x4 c1 = *(const f32x4*)(rp+36);
      f32x4 c2 = *(const f32x4*)(rp+40);
      f32x4 c3 = *(const f32x4*)(rp+44);
      float z = dtbv;
      z += q0[0]*dwq[0]+q0[1]*dwq[1]+q0[2]*dwq[2]+q0[3]*dwq[3];
      z += q1[0]*dwq[4]+q1[1]*dwq[5]+q1[2]*dwq[6]+q1[3]*dwq[7];
      z += q2[0]*dwq[8]+q2[1]*dwq[9]+q2[2]*dwq[10]+q2[3]*dwq[11];
      z += q3[0]*dwq[12]+q3[1]*dwq[13]+q3[2]*dwq[14]+q3[3]*dwq[15];
      float delta = softplus_f(z);
      float xv = (float)xs[row*DI + d];
      float dx = delta*xv;
      float Bv[16] = {b0[0],b0[1],b0[2],b0[3], b1[0],b1[1],b1[2],b1[3],
                      b2[0],b2[1],b2[2],b2[3], b3[0],b3[1],b3[2],b3[3]};
      float Cv[16] = {c0[0],c0[1],c0[2],c0[3], c1[0],c1[1],c1[2],c1[3],
                      c2[0],c2[1],c2[2],c2[3], c3[0],c3[1],c3[2],c3[3]};
      float p = 0.f;
      #pragma unroll
      for (int n=0;n<16;n++){
        h[n] = __expf(delta*A[n])*h[n] + dx*Bv[n];
        p += h[n]*Cv[n];
      }
      float yv = p + Dpv*xv;
      float rv = (float)res[row*DI + d];
      res[row*DI + d] = (__bf16)(yv * silu_f(rv));
    }
  }
}

// ---------------- FALLBACK scan (compact-buffer version) ----------------
__global__ __launch_bounds__(256) void scan_k(
    const float* xd0, const float* xd1,
    const __bf16* xs0, const __bf16* xs1,
    __bf16* res0, __bf16* res1,
    const float* dw0, const float* dw1,
    const __bf16* dtB0, const __bf16* dtB1,
    const __bf16* AL0, const __bf16* AL1,
    const __bf16* Dp0, const __bf16* Dp1)
{
  const int dir = blockIdx.z;
  const float*  xd  = dir ? xd1 : xd0;
  const __bf16* xs  = dir ? xs1 : xs0;
  __bf16*       res = dir ? res1 : res0;
  const float*  dw  = dir ? dw1 : dw0;
  const __bf16* dtB = dir ? dtB1 : dtB0;
  const __bf16* AL  = dir ? AL1 : AL0;
  const __bf16* Dp  = dir ? Dp1 : Dp0;

  const int b  = blockIdx.y;
  const int dt = blockIdx.x;
  const int tid = threadIdx.x;
  const int n  = tid & 15;
  const int dl = tid >> 4;
  const int d  = dt*16 + dl;

  __shared__ float sxd[128][48];
  __shared__ float sx[128][16];
  __shared__ float sdelta[128][16];
  __shared__ float sy[128][16];
  __shared__ float sdw[16][17];
  __shared__ float sdb[16];

  sdw[dl][n] = dw[(dt*16+dl)*DTR + n];
  if (tid < 16) sdb[tid] = (float)dtB[dt*16 + tid];
  const float A_dn = -__expf((float)AL[d*DS + n]);
  float h = 0.f;
  __syncthreads();

  const long rowB = (long)b * L_;
  for (int c0=0; c0<L_; c0+=128){
    #pragma unroll 1
    for (int k=0;k<24;k++){
      int e = tid + k*256;
      int t = e / 48, col = e - t*48;
      sxd[t][col] = xd[(rowB + c0 + t)*48 + col];
    }
    #pragma unroll 1
    for (int k=0;k<8;k++){
      int e = tid + k*256;
      int t = e >> 4, dc = e & 15;
      sx[t][dc] = (float)xs[(rowB + c0 + t)*DI + dt*16 + dc];
    }
    __syncthreads();
    #pragma unroll 1
    for (int k=0;k<8;k++){
      int e = tid + k*256;
      int t = e >> 4, dc = e & 15;
      float z = sdb[dc];
      #pragma unroll
      for (int q=0;q<16;q++) z += sxd[t][q] * sdw[dc][q];
      sdelta[t][dc] = softplus_f(z);
    }
    __syncthreads();
    #pragma unroll 2
    for (int tt=0;tt<128;tt++){
      float delta = sdelta[tt][dl];
      float xv = sx[tt][dl];
      float Bv = sxd[tt][16+n];
      float Cv = sxd[tt][32+n];
      float dA = __expf(delta * A_dn);
      h = dA*h + (delta*xv)*Bv;
      float p = h * Cv;
      p += __shfl_xor(p, 1);
      p += __shfl_xor(p, 2);
      p += __shfl_xor(p, 4);
      p += __shfl_xor(p, 8);
      if (n == 0) sy[tt][dl] = p;
    }
    __syncthreads();
    #pragma unroll 1
    for (int k=0;k<8;k++){
      int e = tid + k*256;
      int t = e >> 4, dc = e & 15;
      long row = rowB + c0 + t;
      float yv = sy[t][dc] + (float)Dp[dt*16+dc] * sx[t][dc];
      float rv = (float)res[row*DI + dt*16 + dc];
      res[row*DI + dt*16 + dc] = (__bf16)(yv * silu_f(rv));
    }
    __syncthreads();
  }
}

// ---------------- launch ----------------
extern "C" void kernel_launch(void* const* d_in, const int* in_sizes, int n_in,
                              void* d_out, int out_size, void* d_ws, size_t ws_size,
                              hipStream_t stream)
{
  const size_t MB = 1u<<20;
  if (ws_size < 61*MB) return;
  const bool newscan = (ws_size >= 112*MB);

  char* w = (char*)d_ws;
  // compact activation buffers
  __bf16* xz[2]  = {(__bf16*)(w + 0),      (__bf16*)(w + 8*MB)};    // pre-conv
  __bf16* res[2] = {(__bf16*)(w + 16*MB),  (__bf16*)(w + 24*MB)};   // gate, then yg in-place
  __bf16* xsc[2] = {(__bf16*)(w + 32*MB),  (__bf16*)(w + 40*MB)};
  __bf16* xn     = (__bf16*)(w + 48*MB);
  float*  xdbl[2]= {(float*)(w + 48*MB),   (float*)(w + 48*MB + (size_t)M_*48*4)};
  __bf16* fusedIn = xsc[0];

  char* wp = w + 52*MB;
  auto carve = [&](size_t bytes)->void*{
    void* p = wp;
    wp += (bytes + 255) & ~(size_t)255;
    return p;
  };
  __bf16 *inWt[2], *xWt[2], *outWt[2];
  float *dtWt[2], *convWt[2];
  for (int m=0;m<2;m++){
    inWt[m]   = (__bf16*)carve((size_t)(2*DI)*DM*2);
    xWt[m]    = (__bf16*)carve((size_t)48*DI*2);
    outWt[m]  = (__bf16*)carve((size_t)DM*DI*2);
    dtWt[m]   = (float*)carve((size_t)DI*DTR*4);
    convWt[m] = (float*)carve((size_t)4*DI*4);
  }
  __bf16* fusWt = (__bf16*)carve((size_t)DM*DI*2);
  int* flag = (int*)carve(256);
  float* ALf[2] = {(float*)carve((size_t)DI*DS*4), (float*)carve((size_t)DI*DS*4)};

  // converted-input arena
  char* cp = w + 54*MB;
  auto carve2 = [&](size_t elems)->__bf16*{
    __bf16* p = (__bf16*)cp;
    cp += (elems*2 + 255) & ~(size_t)255;
    return p;
  };
  __bf16* xc  = carve2((size_t)M_*DM);
  __bf16* ngc = carve2(DM);
  __bf16* nbc = carve2(DM);
  __bf16 *inWc[2], *convWc[2], *convBc[2], *xWc[2], *dtWc[2], *dtBc[2], *ALc[2], *Dpc[2], *outWc[2];
  for (int m=0;m<2;m++){
    inWc[m]   = carve2((size_t)DM*2*DI);
    convWc[m] = carve2((size_t)DI*4);
    convBc[m] = carve2(DI);
    xWc[m]    = carve2((size_t)DI*48);
    dtWc[m]   = carve2((size_t)DTR*DI);
    dtBc[m]   = carve2(DI);
    ALc[m]    = carve2((size_t)DI*DS);
    Dpc[m]    = carve2(DI);
    outWc[m]  = carve2((size_t)DI*DM);
  }
  __bf16* fusWc = carve2((size_t)2*DM*DM);
  __bf16* fusBc = carve2(DM);

  float* hend = (float*)(w + 61*MB);
  float* sumd = (float*)(w + 78*MB);
  float* Hbuf = (float*)(w + 80*MB);

  probe_k<<<1, 256, 0, stream>>>(d_in[0], flag);

  CvtArgs ca;
  int ci = 0;
  ca.j[ci++] = {d_in[0],  xc,  M_*DM};
  ca.j[ci++] = {d_in[1],  ngc, DM};
  ca.j[ci++] = {d_in[2],  nbc, DM};
  for (int m=0;m<2;m++){
    int base = 3 + m*9;
    ca.j[ci++] = {d_in[base+0], inWc[m],   DM*2*DI};
    ca.j[ci++] = {d_in[base+1], convWc[m], DI*4};
    ca.j[ci++] = {d_in[base+2], convBc[m], DI};
    ca.j[ci++] = {d_in[base+3], xWc[m],    DI*48};
    ca.j[ci++] = {d_in[base+4], dtWc[m],   DTR*DI};
    ca.j[ci++] = {d_in[base+5], dtBc[m],   DI};
    ca.j[ci++] = {d_in[base+6], ALc[m],    DI*DS};
    ca.j[ci++] = {d_in[base+7], Dpc[m],    DI};
    ca.j[ci++] = {d_in[base+8], outWc[m],  DI*DM};
  }
  ca.j[ci++] = {d_in[21], fusWc, 2*DM*DM};
  ca.j[ci++] = {d_in[22], fusBc, DM};
  cvt_k<<<3104512/256, 256, 0, stream>>>(ca, flag);
  cvtA_k<<<64, 256, 0, stream>>>(d_in[9], d_in[18], ALf[0], ALf[1], flag);

  PrepArgs pa;
  int ji = 0;
  for (int m=0;m<2;m++){
    pa.j[ji++] = {inWc[m],  inWt[m],  DM,  2*DI, 0};
    pa.j[ji++] = {xWc[m],   xWt[m],   DI,  48,   0};
    pa.j[ji++] = {outWc[m], outWt[m], DI,  DM,   0};
    pa.j[ji++] = {dtWc[m],  dtWt[m],  DTR, DI,   1};
    pa.j[ji++] = {convWc[m],convWt[m],DI,  4,    1};
  }
  pa.j[ji++] = {fusWc, fusWt, DI, DM, 0};
  prep_k<<<(987136+255)/256, 256, 0, stream>>>(pa);

  ln_k<<<M_, 256, 0, stream>>>(xc, ngc, nbc, xn);
  // in-proj: split store into xz (cols<DI) and res (cols>=DI), both compact
  gemm_k<4,4,2,2,0><<<dim3(M_/128, (2*DI)/128, 2), 256, 0, stream>>>(
      xn, xn, inWt[0], inWt[1], xz[0], xz[1], DM, DM, DM, DI, res[0], res[1], nullptr);
  conv_k<<<dim3((M_*64)/256, 1, 2), 256, 0, stream>>>(
      xz[0], xz[1], convWt[0], convWt[1], convBc[0], convBc[1], xsc[0], xsc[1]);
  gemm_k<1,3,4,1,1><<<dim3(M_/64, 1, 2), 256, 0, stream>>>(
      xsc[0], xsc[1], xWt[0], xWt[1], xdbl[0], xdbl[1], DI, DI, DI, 48, nullptr, nullptr, nullptr);

  if (newscan){
    scanA_k<<<dim3(NC*2, B_, 2), 256, 0, stream>>>(
        xdbl[0], xdbl[1], xsc[0], xsc[1], dtWt[0], dtWt[1],
        dtBc[0], dtBc[1], ALf[0], ALf[1], hend, sumd);
    scanB_k<<<131072/256, 256, 0, stream>>>(ALf[0], ALf[1], hend, sumd, Hbuf);
    scanC_k<<<dim3(NC*2, B_, 2), 256, 0, stream>>>(
        xdbl[0], xdbl[1], xsc[0], xsc[1], res[0], res[1],
        dtWt[0], dtWt[1], dtBc[0], dtBc[1], ALf[0], ALf[1], Dpc[0], Dpc[1], Hbuf);
  } else {
    scan_k<<<dim3(DI/16, B_, 2), 256, 0, stream>>>(
        xdbl[0], xdbl[1], xsc[0], xsc[1], res[0], res[1], dtWt[0], dtWt[1],
        dtBc[0], dtBc[1], ALc[0], ALc[1], Dpc[0], Dpc[1]);
  }

  // out-proj: A = yg (res, compact lda=DI); dir1 C-rows un-flipped on store
  gemm_k<4,2,2,2,2><<<dim3(M_/128, DM/64, 2), 256, 0, stream>>>(
      res[0], res[1], outWt[0], outWt[1], fusedIn, fusedIn, DI, DI, DI, 2*DM, nullptr, nullptr, nullptr);
  gemm_k<4,2,2,2,3><<<dim3(M_/128, DM/64, 1), 256, 0, stream>>>(
      fusedIn, fusedIn, fusWt, fusWt, d_out, d_out, 2*DM, 2*DM, 2*DM, DM, fusBc, xc, flag);
}

// Round 7
// 312.938 us; speedup vs baseline: 1.1047x; 1.1047x over previous
//
#include <hip/hip_runtime.h>
#include <cmath>

typedef __bf16 bf16x8 __attribute__((ext_vector_type(8)));
typedef float  f32x4  __attribute__((ext_vector_type(4)));

#define B_  8
#define L_  1024
#define DM  256
#define DI  512
#define DS  16
#define DTR 16
#define M_  (B_*L_)
#define NC  32     // scan chunks
#define CT  32     // steps per chunk

__device__ inline float softplus_f(float z){
  return (z > 20.f) ? z : __logf(1.f + __expf(z));
}
__device__ inline float silu_f(float z){
  return z / (1.f + __expf(-z));
}

// powers e1^(n+1), n=0..15, via depth-4 tree
__device__ inline void pow_tree(float e1, float* p){
  float e2=e1*e1, e4=e2*e2, e8=e4*e4;
  float e3=e2*e1, e5=e4*e1, e6=e4*e2, e7=e4*e3;
  p[0]=e1;  p[1]=e2;  p[2]=e3;  p[3]=e4;
  p[4]=e5;  p[5]=e6;  p[6]=e7;  p[7]=e8;
  p[8]=e8*e1;  p[9]=e8*e2;  p[10]=e8*e3;  p[11]=e8*e4;
  p[12]=e8*e5; p[13]=e8*e6; p[14]=e8*e7;  p[15]=e8*e8;
}

// ---------------- dtype probe: are inputs fp32 or bf16? ----------------
__global__ __launch_bounds__(256) void probe_k(const void* x, int* flag){
  __shared__ int sbad[256];
  int tid = threadIdx.x;
  const unsigned short* u = (const unsigned short*)x;
  int bad = 0;
  for (int i = tid; i < 4096; i += 256){
    unsigned short v = u[2*i];
    int e = (v >> 7) & 0xFF;
    if (e >= 160 || e < 96) bad++;
  }
  sbad[tid] = bad;
  __syncthreads();
  if (tid == 0){
    int t = 0;
    for (int i=0;i<256;i++) t += sbad[i];
    *flag = (t > 1024) ? 1 : 0;   // 1 = inputs are fp32
  }
}

// ---------------- convert all inputs to canonical bf16 ----------------
struct CvtJob { const void* src; __bf16* dst; int n; };
struct CvtArgs { CvtJob j[23]; };

__global__ __launch_bounds__(256) void cvt_k(CvtArgs a, const int* flag){
  int e = blockIdx.x*256 + threadIdx.x;
  const int f = *flag;
  #pragma unroll 1
  for (int jj=0; jj<23; jj++){
    int n = a.j[jj].n;
    if (e < n){
      if (f) a.j[jj].dst[e] = (__bf16)(((const float*)a.j[jj].src)[e]);
      else   a.j[jj].dst[e] = ((const __bf16*)a.j[jj].src)[e];
      return;
    }
    e -= n;
  }
}

// exact-f32 copy of ALog (both dirs)
__global__ __launch_bounds__(256) void cvtA_k(const void* a0, const void* a1,
                                              float* o0, float* o1, const int* flag){
  int gid = blockIdx.x*256 + threadIdx.x;   // 16384
  const int f = *flag;
  const void* src = (gid < 8192) ? a0 : a1;
  float* dst = (gid < 8192) ? o0 : o1;
  int i = gid & 8191;
  dst[i] = f ? ((const float*)src)[i] : (float)((const __bf16*)src)[i];
}

// ---------------- prep: transpose all weight matrices (bf16 in) ----------------
struct PrepJob { const __bf16* src; void* dst; int rows; int cols; int f32out; };
struct PrepArgs { PrepJob j[11]; };

__global__ __launch_bounds__(256) void prep_k(PrepArgs a){
  int e = blockIdx.x*256 + threadIdx.x;
  #pragma unroll 1
  for (int jj=0; jj<11; jj++){
    int sz = a.j[jj].rows * a.j[jj].cols;
    if (e < sz){
      int cols = a.j[jj].cols;
      int r = e / cols, c = e - r*cols;
      float v = (float)a.j[jj].src[e];
      if (a.j[jj].f32out) ((float*)a.j[jj].dst)[c*a.j[jj].rows + r] = v;
      else ((__bf16*)a.j[jj].dst)[(long)c*a.j[jj].rows + r] = (__bf16)v;
      return;
    }
    e -= sz;
  }
}

// ---------------- LayerNorm ----------------
__global__ __launch_bounds__(256) void ln_k(const __bf16* x, const __bf16* g,
                                            const __bf16* bb, __bf16* xn){
  const int row = blockIdx.x;
  const int d = threadIdx.x;
  float v = (float)x[(long)row*DM + d];
  float s = v, q = v*v;
  #pragma unroll
  for (int off=32; off>0; off>>=1){
    s += __shfl_down(s, off);
    q += __shfl_down(q, off);
  }
  __shared__ float ss[4], sq[4];
  int w = d >> 6, ln = d & 63;
  if (ln == 0){ ss[w] = s; sq[w] = q; }
  __syncthreads();
  s = ss[0]+ss[1]+ss[2]+ss[3];
  q = sq[0]+sq[1]+sq[2]+sq[3];
  float mu  = s * (1.f/DM);
  float var = q * (1.f/DM) - mu*mu;
  float xnv = (v - mu) * rsqrtf(var + 1e-5f) * (float)g[d] + (float)bb[d];
  xn[(long)row*DM + d] = (__bf16)xnv;
}

// ---------------- generic MFMA GEMM: C[M][N] = A[M][K] * Bt[N][K]^T ----------------
// EPI 0: split store (c<DI -> C [xz], c>=DI -> res, both ldc=DI); A rows flipped when dir==1
// EPI 1: f32 store
// EPI 2: bf16 store into concat buffer colOff=dir*DM; C rows flipped when dir==1
// EPI 3: store + bias + residual; dtype per *outflag
template<int WMT,int WNT,int BWM,int BWN,int EPI>
__global__ __launch_bounds__(64*BWM*BWN) void gemm_k(
    const __bf16* A0, const __bf16* A1,
    const __bf16* B0, const __bf16* B1,
    void* C0, void* C1,
    int K, int lda, int ldb, int ldc,
    const __bf16* bias, const __bf16* resid, const int* outflag)
{
  const int dir = blockIdx.z;
  const __bf16* A  = dir ? A1 : A0;
  const __bf16* Bt = dir ? B1 : B0;
  char* C = (char*)(dir ? C1 : C0);
  __bf16* resW = (EPI==0) ? (__bf16*)(dir ? resid : bias) : nullptr;
  const int tid  = threadIdx.x;
  const int lane = tid & 63;
  const int wid  = tid >> 6;
  const int wm = wid % BWM;
  const int wn = wid / BWM;
  const int mBase = (blockIdx.x*BWM + wm) * (WMT*16);
  const int nBase = (blockIdx.y*BWN + wn) * (WNT*16);
  const int lm = lane & 15;
  const int kq = (lane >> 4) * 8;
  const int of = (EPI==3 && outflag) ? *outflag : 0;

  long aoff[WMT];
  #pragma unroll
  for (int i=0;i<WMT;i++){
    int r = mBase + i*16 + lm;
    if (EPI==0 && dir==1){ int b = r >> 10, t = r & (L_-1); r = (b<<10) + (L_-1-t); }
    aoff[i] = (long)r * lda + kq;
  }
  long boff[WNT];
  #pragma unroll
  for (int j=0;j<WNT;j++) boff[j] = (long)(nBase + j*16 + lm) * ldb + kq;

  f32x4 acc[WMT][WNT] = {};
  for (int k0=0; k0<K; k0+=32){
    bf16x8 af[WMT], bfr[WNT];
    #pragma unroll
    for (int i=0;i<WMT;i++) af[i]  = *(const bf16x8*)(A  + aoff[i] + k0);
    #pragma unroll
    for (int j=0;j<WNT;j++) bfr[j] = *(const bf16x8*)(Bt + boff[j] + k0);
    #pragma unroll
    for (int i=0;i<WMT;i++)
      #pragma unroll
      for (int j=0;j<WNT;j++)
        acc[i][j] = __builtin_amdgcn_mfma_f32_16x16x32_bf16(af[i], bfr[j], acc[i][j], 0,0,0);
  }

  const int coff = (EPI==2) ? dir*DM : 0;
  #pragma unroll
  for (int i=0;i<WMT;i++){
    #pragma unroll
    for (int rr=0;rr<4;rr++){
      int r = mBase + i*16 + (lane>>4)*4 + rr;
      int rOut = r;
      if (EPI==2 && dir==1){ int b = r >> 10, t = r & (L_-1); rOut = (b<<10) + (L_-1-t); }
      #pragma unroll
      for (int j=0;j<WNT;j++){
        int c = nBase + j*16 + lm;
        float v = acc[i][j][rr];
        if (EPI==0){
          if (c < DI) ((__bf16*)C)[(long)r*DI + c] = (__bf16)v;
          else        resW[(long)r*DI + (c-DI)]    = (__bf16)v;
        } else if (EPI==3){
          v += (float)bias[c] + (float)resid[(long)r*DM + c];
          if (of) ((float*)C)[(long)r*ldc + c] = v;
          else    ((__bf16*)C)[(long)r*ldc + c] = (__bf16)v;
        } else if (EPI==1){
          ((float*)C)[(long)r*ldc + c] = v;
        } else {
          ((__bf16*)C)[(long)rOut*ldc + coff + c] = (__bf16)v;
        }
      }
    }
  }
}

// ---------------- causal depthwise conv (DC=4) + SiLU ----------------
__global__ __launch_bounds__(256) void conv_k(
    const __bf16* xz0, const __bf16* xz1,
    const float* cw0, const float* cw1,
    const __bf16* cb0, const __bf16* cb1,
    __bf16* xs0, __bf16* xs1)
{
  const int dir = blockIdx.z;
  const __bf16* xz = dir ? xz1 : xz0;
  const float*  cw = dir ? cw1 : cw0;
  const __bf16* cb = dir ? cb1 : cb0;
  __bf16* xs = dir ? xs1 : xs0;

  int gid = blockIdx.x*256 + threadIdx.x;
  int c8 = gid & 63;
  int t  = (gid >> 6) & (L_-1);
  int b  = gid >> 16;
  int cbase = c8*8;

  float acc[8];
  bf16x8 bb = *(const bf16x8*)(cb + cbase);
  #pragma unroll
  for (int c=0;c<8;c++) acc[c] = (float)bb[c];
  #pragma unroll
  for (int j=0;j<4;j++){
    int tj = t - 3 + j;
    if (tj >= 0){
      bf16x8 xv = *(const bf16x8*)(xz + ((long)(b*L_ + tj))*DI + cbase);
      #pragma unroll
      for (int c=0;c<8;c++) acc[c] += (float)xv[c] * cw[j*DI + cbase + c];
    }
  }
  bf16x8 outv;
  #pragma unroll
  for (int c=0;c<8;c++) outv[c] = (__bf16)silu_f(acc[c]);
  *(bf16x8*)(xs + ((long)(b*L_ + t))*DI + cbase) = outv;
}

// ============ scan phase A: local scan + chunk summaries + delta store ============
// LDS broadcast staging (measured faster than wave-uniform global loads, r5 vs r6).
__global__ __launch_bounds__(256) void scanA_k(
    const float* xd0, const float* xd1,
    const __bf16* xs0, const __bf16* xs1,
    const float* dw0, const float* dw1,
    const __bf16* dtB0, const __bf16* dtB1,
    const float* ALf0, const float* ALf1,
    float* dg0, float* dg1,                // delta out [M][DI] f32
    float* hend, float* sumd)
{
  const int dir = blockIdx.z;
  const float*  xd  = dir ? xd1 : xd0;
  const __bf16* xs  = dir ? xs1 : xs0;
  const float*  dw  = dir ? dw1 : dw0;
  const __bf16* dtB = dir ? dtB1 : dtB0;
  const float*  ALf = dir ? ALf1 : ALf0;
  float* dg = dir ? dg1 : dg0;

  const int b   = blockIdx.y;
  const int c   = blockIdx.x >> 1;
  const int dg_ = blockIdx.x & 1;
  const int tid = threadIdx.x;
  const int d   = dg_*256 + tid;
  const int db  = dir*8 + b;
  const long row0 = (long)b*L_ + c*CT;

  __shared__ float sAB[CT][32];   // xd cols 0..31: dlt | B

  { int e = tid*4; int t = e>>5, cc = e&31;
    *(f32x4*)&sAB[t][cc] = *(const f32x4*)(xd + (row0+t)*48 + cc); }

  float dwq[16];
  { const f32x4* p = (const f32x4*)(dw + d*DTR);
    #pragma unroll
    for (int q=0;q<4;q++){ f32x4 v=p[q]; dwq[q*4]=v[0]; dwq[q*4+1]=v[1]; dwq[q*4+2]=v[2]; dwq[q*4+3]=v[3]; } }
  float A[16];
  { const f32x4* p = (const f32x4*)(ALf + d*DS);
    #pragma unroll
    for (int q=0;q<4;q++){ f32x4 v=p[q];
      A[q*4]=-__expf(v[0]); A[q*4+1]=-__expf(v[1]); A[q*4+2]=-__expf(v[2]); A[q*4+3]=-__expf(v[3]); } }
  bool pow_ok = true;
  #pragma unroll
  for (int n=0;n<16;n++) pow_ok = pow_ok && (fabsf(A[n] + (float)(n+1)) < 0.003f*(n+1));
  const float dtbv = (float)dtB[d];

  float h[16];
  #pragma unroll
  for (int n=0;n<16;n++) h[n]=0.f;
  float sdelta = 0.f;
  __syncthreads();

  if (pow_ok){
    #pragma unroll 2
    for (int t=0;t<CT;t++){
      f32x4 q0 = *(const f32x4*)&sAB[t][0];
      f32x4 q1 = *(const f32x4*)&sAB[t][4];
      f32x4 q2 = *(const f32x4*)&sAB[t][8];
      f32x4 q3 = *(const f32x4*)&sAB[t][12];
      f32x4 b0 = *(const f32x4*)&sAB[t][16];
      f32x4 b1 = *(const f32x4*)&sAB[t][20];
      f32x4 b2 = *(const f32x4*)&sAB[t][24];
      f32x4 b3 = *(const f32x4*)&sAB[t][28];
      float z = dtbv;
      z += q0[0]*dwq[0]+q0[1]*dwq[1]+q0[2]*dwq[2]+q0[3]*dwq[3];
      z += q1[0]*dwq[4]+q1[1]*dwq[5]+q1[2]*dwq[6]+q1[3]*dwq[7];
      z += q2[0]*dwq[8]+q2[1]*dwq[9]+q2[2]*dwq[10]+q2[3]*dwq[11];
      z += q3[0]*dwq[12]+q3[1]*dwq[13]+q3[2]*dwq[14]+q3[3]*dwq[15];
      float delta = softplus_f(z);
      dg[(row0+t)*DI + d] = delta;
      sdelta += delta;
      float xv = (float)xs[(row0+t)*DI + d];
      float dx = delta*xv;
      float pw[16];
      pow_tree(__expf(-delta), pw);
      float Bv[16] = {b0[0],b0[1],b0[2],b0[3], b1[0],b1[1],b1[2],b1[3],
                      b2[0],b2[1],b2[2],b2[3], b3[0],b3[1],b3[2],b3[3]};
      #pragma unroll
      for (int n=0;n<16;n++)
        h[n] = pw[n]*h[n] + dx*Bv[n];
    }
  } else {
    #pragma unroll 2
    for (int t=0;t<CT;t++){
      f32x4 q0 = *(const f32x4*)&sAB[t][0];
      f32x4 q1 = *(const f32x4*)&sAB[t][4];
      f32x4 q2 = *(const f32x4*)&sAB[t][8];
      f32x4 q3 = *(const f32x4*)&sAB[t][12];
      f32x4 b0 = *(const f32x4*)&sAB[t][16];
      f32x4 b1 = *(const f32x4*)&sAB[t][20];
      f32x4 b2 = *(const f32x4*)&sAB[t][24];
      f32x4 b3 = *(const f32x4*)&sAB[t][28];
      float z = dtbv;
      z += q0[0]*dwq[0]+q0[1]*dwq[1]+q0[2]*dwq[2]+q0[3]*dwq[3];
      z += q1[0]*dwq[4]+q1[1]*dwq[5]+q1[2]*dwq[6]+q1[3]*dwq[7];
      z += q2[0]*dwq[8]+q2[1]*dwq[9]+q2[2]*dwq[10]+q2[3]*dwq[11];
      z += q3[0]*dwq[12]+q3[1]*dwq[13]+q3[2]*dwq[14]+q3[3]*dwq[15];
      float delta = softplus_f(z);
      dg[(row0+t)*DI + d] = delta;
      sdelta += delta;
      float xv = (float)xs[(row0+t)*DI + d];
      float dx = delta*xv;
      float Bv[16] = {b0[0],b0[1],b0[2],b0[3], b1[0],b1[1],b1[2],b1[3],
                      b2[0],b2[1],b2[2],b2[3], b3[0],b3[1],b3[2],b3[3]};
      #pragma unroll
      for (int n=0;n<16;n++)
        h[n] = __expf(delta*A[n])*h[n] + dx*Bv[n];
    }
  }

  long hb = (((long)db*NC + c)*DI + d)*16;
  f32x4* hp = (f32x4*)(hend + hb);
  #pragma unroll
  for (int q=0;q<4;q++){ f32x4 v; v[0]=h[q*4]; v[1]=h[q*4+1]; v[2]=h[q*4+2]; v[3]=h[q*4+3]; hp[q]=v; }
  sumd[((long)db*NC + c)*DI + d] = sdelta;
}

// ============ phase B: chain chunk summaries sequentially ============
__global__ __launch_bounds__(256) void scanB_k(
    const float* ALf0, const float* ALf1,
    const float* hend, const float* sumd, float* Hbuf)
{
  int gid = blockIdx.x*256 + threadIdx.x;   // 131072
  int n  = gid & 15;
  int d  = (gid>>4) & 511;
  int db = gid >> 13;
  const float* ALf = (db>=8) ? ALf1 : ALf0;
  float A_dn = -__expf(ALf[d*DS + n]);
  float H = 0.f;
  #pragma unroll 1
  for (int c=0;c<NC;c++){
    long base = (((long)db*NC + c)*DI + d)*16 + n;
    Hbuf[base] = H;
    float S = sumd[((long)db*NC + c)*DI + d];
    H = hend[base] + __expf(A_dn*S)*H;
  }
}

// ============ phase C: re-scan seeded from Hbuf; y + gate; in-place into res ============
__global__ __launch_bounds__(256) void scanC_k(
    const float* xd0, const float* xd1,
    const __bf16* xs0, const __bf16* xs1,
    __bf16* res0, __bf16* res1,
    const float* dg0, const float* dg1,    // delta in
    const float* ALf0, const float* ALf1,
    const __bf16* Dp0, const __bf16* Dp1,
    const float* Hbuf)
{
  const int dir = blockIdx.z;
  const float*  xd  = dir ? xd1 : xd0;
  const __bf16* xs  = dir ? xs1 : xs0;
  __bf16*       res = dir ? res1 : res0;
  const float*  dg  = dir ? dg1 : dg0;
  const float*  ALf = dir ? ALf1 : ALf0;
  const __bf16* Dp  = dir ? Dp1 : Dp0;

  const int b   = blockIdx.y;
  const int c   = blockIdx.x >> 1;
  const int dg_ = blockIdx.x & 1;
  const int tid = threadIdx.x;
  const int d   = dg_*256 + tid;
  const int db  = dir*8 + b;
  const long row0 = (long)b*L_ + c*CT;

  __shared__ float sBC[CT][32];   // xd cols 16..47: B | C

  { int e = tid*4; int t = e>>5, cc = e&31;
    *(f32x4*)&sBC[t][cc] = *(const f32x4*)(xd + (row0+t)*48 + 16 + cc); }

  float A[16];
  { const f32x4* p = (const f32x4*)(ALf + d*DS);
    #pragma unroll
    for (int q=0;q<4;q++){ f32x4 v=p[q];
      A[q*4]=-__expf(v[0]); A[q*4+1]=-__expf(v[1]); A[q*4+2]=-__expf(v[2]); A[q*4+3]=-__expf(v[3]); } }
  bool pow_ok = true;
  #pragma unroll
  for (int n=0;n<16;n++) pow_ok = pow_ok && (fabsf(A[n] + (float)(n+1)) < 0.003f*(n+1));

  float h[16];
  { long hb = (((long)db*NC + c)*DI + d)*16;
    const f32x4* p = (const f32x4*)(Hbuf + hb);
    #pragma unroll
    for (int q=0;q<4;q++){ f32x4 v = p[q]; h[q*4]=v[0]; h[q*4+1]=v[1]; h[q*4+2]=v[2]; h[q*4+3]=v[3]; } }
  const float Dpv = (float)Dp[d];
  __syncthreads();

  if (pow_ok){
    #pragma unroll 2
    for (int t=0;t<CT;t++){
      long row = row0 + t;
      f32x4 b0 = *(const f32x4*)&sBC[t][0];
      f32x4 b1 = *(const f32x4*)&sBC[t][4];
      f32x4 b2 = *(const f32x4*)&sBC[t][8];
      f32x4 b3 = *(const f32x4*)&sBC[t][12];
      f32x4 c0 = *(const f32x4*)&sBC[t][16];
      f32x4 c1 = *(const f32x4*)&sBC[t][20];
      f32x4 c2 = *(const f32x4*)&sBC[t][24];
      f32x4 c3 = *(const f32x4*)&sBC[t][28];
      float delta = dg[row*DI + d];
      float xv = (float)xs[row*DI + d];
      float dx = delta*xv;
      float pw[16];
      pow_tree(__expf(-delta), pw);
      float Bv[16] = {b0[0],b0[1],b0[2],b0[3], b1[0],b1[1],b1[2],b1[3],
                      b2[0],b2[1],b2[2],b2[3], b3[0],b3[1],b3[2],b3[3]};
      float Cv[16] = {c0[0],c0[1],c0[2],c0[3], c1[0],c1[1],c1[2],c1[3],
                      c2[0],c2[1],c2[2],c2[3], c3[0],c3[1],c3[2],c3[3]};
      float p = 0.f;
      #pragma unroll
      for (int n=0;n<16;n++){
        h[n] = pw[n]*h[n] + dx*Bv[n];
        p += h[n]*Cv[n];
      }
      float yv = p + Dpv*xv;
      float rv = (float)res[row*DI + d];
      res[row*DI + d] = (__bf16)(yv * silu_f(rv));
    }
  } else {
    #pragma unroll 2
    for (int t=0;t<CT;t++){
      long row = row0 + t;
      f32x4 b0 = *(const f32x4*)&sBC[t][0];
      f32x4 b1 = *(const f32x4*)&sBC[t][4];
      f32x4 b2 = *(const f32x4*)&sBC[t][8];
      f32x4 b3 = *(const f32x4*)&sBC[t][12];
      f32x4 c0 = *(const f32x4*)&sBC[t][16];
      f32x4 c1 = *(const f32x4*)&sBC[t][20];
      f32x4 c2 = *(const f32x4*)&sBC[t][24];
      f32x4 c3 = *(const f32x4*)&sBC[t][28];
      float delta = dg[row*DI + d];
      float xv = (float)xs[row*DI + d];
      float dx = delta*xv;
      float Bv[16] = {b0[0],b0[1],b0[2],b0[3], b1[0],b1[1],b1[2],b1[3],
                      b2[0],b2[1],b2[2],b2[3], b3[0],b3[1],b3[2],b3[3]};
      float Cv[16] = {c0[0],c0[1],c0[2],c0[3], c1[0],c1[1],c1[2],c1[3],
                      c2[0],c2[1],c2[2],c2[3], c3[0],c3[1],c3[2],c3[3]};
      float p = 0.f;
      #pragma unroll
      for (int n=0;n<16;n++){
        h[n] = __expf(delta*A[n])*h[n] + dx*Bv[n];
        p += h[n]*Cv[n];
      }
      float yv = p + Dpv*xv;
      float rv = (float)res[row*DI + d];
      res[row*DI + d] = (__bf16)(yv * silu_f(rv));
    }
  }
}

// ---------------- FALLBACK scan (compact-buffer version) ----------------
__global__ __launch_bounds__(256) void scan_k(
    const float* xd0, const float* xd1,
    const __bf16* xs0, const __bf16* xs1,
    __bf16* res0, __bf16* res1,
    const float* dw0, const float* dw1,
    const __bf16* dtB0, const __bf16* dtB1,
    const __bf16* AL0, const __bf16* AL1,
    const __bf16* Dp0, const __bf16* Dp1)
{
  const int dir = blockIdx.z;
  const float*  xd  = dir ? xd1 : xd0;
  const __bf16* xs  = dir ? xs1 : xs0;
  __bf16*       res = dir ? res1 : res0;
  const float*  dw  = dir ? dw1 : dw0;
  const __bf16* dtB = dir ? dtB1 : dtB0;
  const __bf16* AL  = dir ? AL1 : AL0;
  const __bf16* Dp  = dir ? Dp1 : Dp0;

  const int b  = blockIdx.y;
  const int dt = blockIdx.x;
  const int tid = threadIdx.x;
  const int n  = tid & 15;
  const int dl = tid >> 4;
  const int d  = dt*16 + dl;

  __shared__ float sxd[128][48];
  __shared__ float sx[128][16];
  __shared__ float sdelta[128][16];
  __shared__ float sy[128][16];
  __shared__ float sdw[16][17];
  __shared__ float sdb[16];

  sdw[dl][n] = dw[(dt*16+dl)*DTR + n];
  if (tid < 16) sdb[tid] = (float)dtB[dt*16 + tid];
  const float A_dn = -__expf((float)AL[d*DS + n]);
  float h = 0.f;
  __syncthreads();

  const long rowB = (long)b * L_;
  for (int c0=0; c0<L_; c0+=128){
    #pragma unroll 1
    for (int k=0;k<24;k++){
      int e = tid + k*256;
      int t = e / 48, col = e - t*48;
      sxd[t][col] = xd[(rowB + c0 + t)*48 + col];
    }
    #pragma unroll 1
    for (int k=0;k<8;k++){
      int e = tid + k*256;
      int t = e >> 4, dc = e & 15;
      sx[t][dc] = (float)xs[(rowB + c0 + t)*DI + dt*16 + dc];
    }
    __syncthreads();
    #pragma unroll 1
    for (int k=0;k<8;k++){
      int e = tid + k*256;
      int t = e >> 4, dc = e & 15;
      float z = sdb[dc];
      #pragma unroll
      for (int q=0;q<16;q++) z += sxd[t][q] * sdw[dc][q];
      sdelta[t][dc] = softplus_f(z);
    }
    __syncthreads();
    #pragma unroll 2
    for (int tt=0;tt<128;tt++){
      float delta = sdelta[tt][dl];
      float xv = sx[tt][dl];
      float Bv = sxd[tt][16+n];
      float Cv = sxd[tt][32+n];
      float dA = __expf(delta * A_dn);
      h = dA*h + (delta*xv)*Bv;
      float p = h * Cv;
      p += __shfl_xor(p, 1);
      p += __shfl_xor(p, 2);
      p += __shfl_xor(p, 4);
      p += __shfl_xor(p, 8);
      if (n == 0) sy[tt][dl] = p;
    }
    __syncthreads();
    #pragma unroll 1
    for (int k=0;k<8;k++){
      int e = tid + k*256;
      int t = e >> 4, dc = e & 15;
      long row = rowB + c0 + t;
      float yv = sy[t][dc] + (float)Dp[dt*16+dc] * sx[t][dc];
      float rv = (float)res[row*DI + dt*16 + dc];
      res[row*DI + dt*16 + dc] = (__bf16)(yv * silu_f(rv));
    }
    __syncthreads();
  }
}

// ---------------- launch ----------------
extern "C" void kernel_launch(void* const* d_in, const int* in_sizes, int n_in,
                              void* d_out, int out_size, void* d_ws, size_t ws_size,
                              hipStream_t stream)
{
  const size_t MB = 1u<<20;
  if (ws_size < 61*MB) return;
  const bool newscan = (ws_size >= 112*MB);

  char* w = (char*)d_ws;
  __bf16* xz[2]  = {(__bf16*)(w + 0),      (__bf16*)(w + 8*MB)};    // pre-conv (dead after conv)
  __bf16* res[2] = {(__bf16*)(w + 16*MB),  (__bf16*)(w + 24*MB)};   // gate, then yg in-place
  __bf16* xsc[2] = {(__bf16*)(w + 32*MB),  (__bf16*)(w + 40*MB)};
  __bf16* xn     = (__bf16*)(w + 48*MB);
  float*  xdbl[2]= {(float*)(w + 48*MB),   (float*)(w + 48*MB + (size_t)M_*48*4)};
  __bf16* fusedIn = xsc[0];

  char* wp = w + 52*MB;
  auto carve = [&](size_t bytes)->void*{
    void* p = wp;
    wp += (bytes + 255) & ~(size_t)255;
    return p;
  };
  __bf16 *inWt[2], *xWt[2], *outWt[2];
  float *dtWt[2], *convWt[2];
  for (int m=0;m<2;m++){
    inWt[m]   = (__bf16*)carve((size_t)(2*DI)*DM*2);
    xWt[m]    = (__bf16*)carve((size_t)48*DI*2);
    outWt[m]  = (__bf16*)carve((size_t)DM*DI*2);
    dtWt[m]   = (float*)carve((size_t)DI*DTR*4);
    convWt[m] = (float*)carve((size_t)4*DI*4);
  }
  __bf16* fusWt = (__bf16*)carve((size_t)DM*DI*2);
  int* flag = (int*)carve(256);
  float* ALf[2] = {(float*)carve((size_t)DI*DS*4), (float*)carve((size_t)DI*DS*4)};

  // converted-input arena
  char* cp = w + 54*MB;
  auto carve2 = [&](size_t elems)->__bf16*{
    __bf16* p = (__bf16*)cp;
    cp += (elems*2 + 255) & ~(size_t)255;
    return p;
  };
  __bf16* xc  = carve2((size_t)M_*DM);
  __bf16* ngc = carve2(DM);
  __bf16* nbc = carve2(DM);
  __bf16 *inWc[2], *convWc[2], *convBc[2], *xWc[2], *dtWc[2], *dtBc[2], *ALc[2], *Dpc[2], *outWc[2];
  for (int m=0;m<2;m++){
    inWc[m]   = carve2((size_t)DM*2*DI);
    convWc[m] = carve2((size_t)DI*4);
    convBc[m] = carve2(DI);
    xWc[m]    = carve2((size_t)DI*48);
    dtWc[m]   = carve2((size_t)DTR*DI);
    dtBc[m]   = carve2(DI);
    ALc[m]    = carve2((size_t)DI*DS);
    Dpc[m]    = carve2(DI);
    outWc[m]  = carve2((size_t)DI*DM);
  }
  __bf16* fusWc = carve2((size_t)2*DM*DM);
  __bf16* fusBc = carve2(DM);

  // scan arena: hend [61,77.8), sumd [78,79), Hbuf [79,95.8), delta1 [96,112)
  float* hend = (float*)(w + 61*MB);
  float* sumd = (float*)(w + 78*MB);
  float* Hbuf = (float*)(w + 79*MB);
  float* dgA[2] = {(float*)(w + 0), (float*)(w + 96*MB)};   // dgA[0] overlays dead xz

  probe_k<<<1, 256, 0, stream>>>(d_in[0], flag);

  CvtArgs ca;
  int ci = 0;
  ca.j[ci++] = {d_in[0],  xc,  M_*DM};
  ca.j[ci++] = {d_in[1],  ngc, DM};
  ca.j[ci++] = {d_in[2],  nbc, DM};
  for (int m=0;m<2;m++){
    int base = 3 + m*9;
    ca.j[ci++] = {d_in[base+0], inWc[m],   DM*2*DI};
    ca.j[ci++] = {d_in[base+1], convWc[m], DI*4};
    ca.j[ci++] = {d_in[base+2], convBc[m], DI};
    ca.j[ci++] = {d_in[base+3], xWc[m],    DI*48};
    ca.j[ci++] = {d_in[base+4], dtWc[m],   DTR*DI};
    ca.j[ci++] = {d_in[base+5], dtBc[m],   DI};
    ca.j[ci++] = {d_in[base+6], ALc[m],    DI*DS};
    ca.j[ci++] = {d_in[base+7], Dpc[m],    DI};
    ca.j[ci++] = {d_in[base+8], outWc[m],  DI*DM};
  }
  ca.j[ci++] = {d_in[21], fusWc, 2*DM*DM};
  ca.j[ci++] = {d_in[22], fusBc, DM};
  cvt_k<<<3104512/256, 256, 0, stream>>>(ca, flag);
  cvtA_k<<<64, 256, 0, stream>>>(d_in[9], d_in[18], ALf[0], ALf[1], flag);

  PrepArgs pa;
  int ji = 0;
  for (int m=0;m<2;m++){
    pa.j[ji++] = {inWc[m],  inWt[m],  DM,  2*DI, 0};
    pa.j[ji++] = {xWc[m],   xWt[m],   DI,  48,   0};
    pa.j[ji++] = {outWc[m], outWt[m], DI,  DM,   0};
    pa.j[ji++] = {dtWc[m],  dtWt[m],  DTR, DI,   1};
    pa.j[ji++] = {convWc[m],convWt[m],DI,  4,    1};
  }
  pa.j[ji++] = {fusWc, fusWt, DI, DM, 0};
  prep_k<<<(987136+255)/256, 256, 0, stream>>>(pa);

  ln_k<<<M_, 256, 0, stream>>>(xc, ngc, nbc, xn);
  gemm_k<4,4,2,2,0><<<dim3(M_/128, (2*DI)/128, 2), 256, 0, stream>>>(
      xn, xn, inWt[0], inWt[1], xz[0], xz[1], DM, DM, DM, DI, res[0], res[1], nullptr);
  conv_k<<<dim3((M_*64)/256, 1, 2), 256, 0, stream>>>(
      xz[0], xz[1], convWt[0], convWt[1], convBc[0], convBc[1], xsc[0], xsc[1]);
  gemm_k<1,3,4,1,1><<<dim3(M_/64, 1, 2), 256, 0, stream>>>(
      xsc[0], xsc[1], xWt[0], xWt[1], xdbl[0], xdbl[1], DI, DI, DI, 48, nullptr, nullptr, nullptr);

  if (newscan){
    scanA_k<<<dim3(NC*2, B_, 2), 256, 0, stream>>>(
        xdbl[0], xdbl[1], xsc[0], xsc[1], dtWt[0], dtWt[1],
        dtBc[0], dtBc[1], ALf[0], ALf[1], dgA[0], dgA[1], hend, sumd);
    scanB_k<<<131072/256, 256, 0, stream>>>(ALf[0], ALf[1], hend, sumd, Hbuf);
    scanC_k<<<dim3(NC*2, B_, 2), 256, 0, stream>>>(
        xdbl[0], xdbl[1], xsc[0], xsc[1], res[0], res[1],
        dgA[0], dgA[1], ALf[0], ALf[1], Dpc[0], Dpc[1], Hbuf);
  } else {
    scan_k<<<dim3(DI/16, B_, 2), 256, 0, stream>>>(
        xdbl[0], xdbl[1], xsc[0], xsc[1], res[0], res[1], dtWt[0], dtWt[1],
        dtBc[0], dtBc[1], ALc[0], ALc[1], Dpc[0], Dpc[1]);
  }

  gemm_k<4,2,2,2,2><<<dim3(M_/128, DM/64, 2), 256, 0, stream>>>(
      res[0], res[1], outWt[0], outWt[1], fusedIn, fusedIn, DI, DI, DI, 2*DM, nullptr, nullptr, nullptr);
  gemm_k<4,2,2,2,3><<<dim3(M_/128, DM/64, 1), 256, 0, stream>>>(
      fusedIn, fusedIn, fusWt, fusWt, d_out, d_out, 2*DM, 2*DM, 2*DM, DM, fusBc, xc, flag);
}